// Round 7
// baseline (62053.589 us; speedup 1.0000x reference)
//
#include <hip/hip_runtime.h>
#include <cstdint>
#include <cstddef>

// Problem constants
#define NN 32768
#define DD 16

__device__ __forceinline__ float sigf(float x) { return 1.0f / (1.0f + __expf(-x)); }
__device__ __forceinline__ float tanhfast(float x) { return 1.0f - 2.0f / (1.0f + __expf(2.0f * x)); }

__device__ __forceinline__ float4 fma4(float4 a, float4 b, float4 c) {
    c.x = fmaf(a.x, b.x, c.x);
    c.y = fmaf(a.y, b.y, c.y);
    c.z = fmaf(a.z, b.z, c.z);
    c.w = fmaf(a.w, b.w, c.w);
    return c;
}

// CK-style barrier: drains LDS counters ONLY (no vmcnt(0)) so global prefetch
// loads / streaming stores stay in flight across the per-step barriers.
__device__ __forceinline__ void sync_lds() {
    asm volatile("s_waitcnt lgkmcnt(0)\n\ts_barrier" ::: "memory");
}

// repetition macros
#define REPP8(M) M(0,1) M(2,3) M(4,5) M(6,7) M(8,9) M(10,11) M(12,13) M(14,15)
#define REP16(M) M(0) M(1) M(2) M(3) M(4) M(5) M(6) M(7) M(8) M(9) M(10) M(11) M(12) M(13) M(14) M(15)
#define REP8L(M) M(0) M(1) M(2) M(3) M(4) M(5) M(6) M(7)

// ---------------------------------------------------------------------------
// GEMM: out[m][n] = sum_k X[m][k] * W[n][k] + b1[n] + b2[n]
// ---------------------------------------------------------------------------
template <int K>
__global__ __launch_bounds__(256) void gemm_bias(const float* __restrict__ X,
                                                 const float* __restrict__ W,
                                                 const float* __restrict__ b1,
                                                 const float* __restrict__ b2,
                                                 float* __restrict__ out, int N) {
    __shared__ __align__(16) float As[64][68];
    __shared__ __align__(16) float Bs[64][68];
    int tid = threadIdx.x;
    int m0 = blockIdx.x * 64, n0 = blockIdx.y * 64;
    int tx = tid & 15, ty = tid >> 4;
    float acc[4][4] = {};
    for (int kc = 0; kc < K; kc += 64) {
#pragma unroll
        for (int e = 0; e < 4; e++) {
            int idx = e * 256 + tid;
            int row = idx >> 4;
            int kb = (idx & 15) * 4;
            *(float4*)&As[row][kb] = *(const float4*)(X + (size_t)(m0 + row) * K + kc + kb);
            *(float4*)&Bs[row][kb] = *(const float4*)(W + (size_t)(n0 + row) * K + kc + kb);
        }
        __syncthreads();
#pragma unroll 8
        for (int k = 0; k < 64; k++) {
            float a[4], b[4];
#pragma unroll
            for (int i = 0; i < 4; i++) a[i] = As[ty * 4 + i][k];
#pragma unroll
            for (int i = 0; i < 4; i++) b[i] = Bs[tx * 4 + i][k];
#pragma unroll
            for (int i = 0; i < 4; i++)
#pragma unroll
                for (int jj = 0; jj < 4; jj++) acc[i][jj] = fmaf(a[i], b[jj], acc[i][jj]);
        }
        __syncthreads();
    }
#pragma unroll
    for (int jj = 0; jj < 4; jj++) {
        int n = n0 + tx * 4 + jj;
        float bb = b1[n] + b2[n];
#pragma unroll
        for (int i = 0; i < 4; i++) {
            out[(size_t)(m0 + ty * 4 + i) * N + n] = acc[i][jj] + bb;
        }
    }
}

// ---------------------------------------------------------------------------
// Batched r-LSTM (T=16, H=128) — unchanged (not the current bottleneck).
// ---------------------------------------------------------------------------
__global__ __launch_bounds__(1024) void rlstm_kernel(const float* __restrict__ XGX,
                                                     const int* __restrict__ nbr,
                                                     const float* __restrict__ Whh,
                                                     float* __restrict__ hagg) {
    __shared__ __align__(16) float h_s[16][128];
    __shared__ __align__(16) float g_s[16][512];
    __shared__ int node_s[16];
    int tid = threadIdx.x;
    int j = tid >> 1;       // gate col 0..511
    int half = tid & 1;     // K half
    const float4* wp = (const float4*)(Whh + (size_t)j * 128 + half * 64);
#define DECLRW(i, jj) float4 rw##i = wp[i], rw##jj = wp[jj];
    REPP8(DECLRW)
#undef DECLRW

    float c0 = 0.f, c1 = 0.f;
    for (int e = tid; e < 16 * 128; e += 1024) ((float*)h_s)[e] = 0.f;
    int r0 = blockIdx.x * 16;
    __syncthreads();

    for (int t = 0; t < DD; t++) {
        if (tid < 16) node_s[tid] = nbr[(size_t)(r0 + tid) * DD + t];
        for (int r = 0; r < 16; r++) {
            const float4* hp = (const float4*)(&h_s[r][half * 64]);
            float4 a0 = {0, 0, 0, 0}, a1 = {0, 0, 0, 0};
#define RDOT(i, jj) { float4 h0 = hp[i], h1 = hp[jj]; a0 = fma4(rw##i, h0, a0); a1 = fma4(rw##jj, h1, a1); }
            REPP8(RDOT)
#undef RDOT
            float s = (a0.x + a0.y) + (a0.z + a0.w) + ((a1.x + a1.y) + (a1.z + a1.w));
            s += __shfl_xor(s, 1, 64);
            if (half == 0) g_s[r][j] = s;
        }
        __syncthreads();
#pragma unroll
        for (int p = 0; p < 2; p++) {
            int idx = tid + p * 1024;
            int r = idx >> 7, hc = idx & 127;
            const float* xrow = XGX + (size_t)node_s[r] * 512;
            float gi = g_s[r][hc] + xrow[hc];
            float gf = g_s[r][128 + hc] + xrow[128 + hc];
            float gg = g_s[r][256 + hc] + xrow[256 + hc];
            float go = g_s[r][384 + hc] + xrow[384 + hc];
            float c = (p == 0) ? c0 : c1;
            c = sigf(gf) * c + sigf(gi) * tanhfast(gg);
            if (p == 0) c0 = c; else c1 = c;
            h_s[r][hc] = sigf(go) * tanhfast(c);
        }
        __syncthreads();
    }
#pragma unroll
    for (int p = 0; p < 2; p++) {
        int idx = tid + p * 1024;
        int r = idx >> 7, hc = idx & 127;
        hagg[(size_t)(r0 + r) * 128 + hc] = h_s[r][hc];
    }
}

// ---------------------------------------------------------------------------
// Sequential o-LSTM, H=128. 512 threads (8 waves, 2/SIMD, 256-VGPR budget).
// thread = (unit n = tid>>2, gate-pair gp = (tid>>1)&1, K-half kh = tid&1):
// 2 gate cols x 64 K. Weights as 128 NAMED SCALAR floats (R6 post-mortem:
// quad-aligned float4 weight tuples caused register-class fragmentation ->
// allocator spilled at VGPR=92 despite 256 budget; scalars pack freely).
// h in LDS, double-buffered, staggered dual-copy (0 bank conflicts, R6).
// One lgkmcnt-only barrier/step; 2-step unroll; xg prefetched 2 ahead;
// HS stores stream (never barrier-drained).
// ---------------------------------------------------------------------------
__global__ __launch_bounds__(512, 2) void olstm128_kernel(const float* __restrict__ XGO,
                                                          const float* __restrict__ Whh,
                                                          float* __restrict__ HS) {
    __shared__ __align__(16) float h_s[2][272];
    const int tid = threadIdx.x;
    const int kh = tid & 1;
    const int gp = (tid >> 1) & 1;   // 0: gates (i,f)  1: gates (g,o)
    const int n = tid >> 2;          // 0..127

    const float4* wap = (const float4*)(Whh + (size_t)(gp * 256 + n) * 128 + kh * 64);
    const float4* wbp = (const float4*)(Whh + (size_t)(gp * 256 + 128 + n) * 128 + kh * 64);
#define DWS(m) float4 ta##m = wap[m], tb##m = wbp[m];                                             \
    float wa##m##_0 = ta##m.x, wa##m##_1 = ta##m.y, wa##m##_2 = ta##m.z, wa##m##_3 = ta##m.w;     \
    float wb##m##_0 = tb##m.x, wb##m##_1 = tb##m.y, wb##m##_2 = tb##m.z, wb##m##_3 = tb##m.w;
    REP16(DWS)
#undef DWS
#define PIN(m) asm volatile("" : "+v"(wa##m##_0), "+v"(wa##m##_1), "+v"(wa##m##_2), "+v"(wa##m##_3), \
                                 "+v"(wb##m##_0), "+v"(wb##m##_1), "+v"(wb##m##_2), "+v"(wb##m##_3));
    REP16(PIN)
#undef PIN

    for (int e = tid; e < 2 * 272; e += 512) ((float*)h_s)[e] = 0.f;
    float c = 0.f;

    float pa0 = XGO[(size_t)0 * 512 + gp * 256 + n], pb0 = XGO[(size_t)0 * 512 + gp * 256 + 128 + n];
    float pa1 = XGO[(size_t)1 * 512 + gp * 256 + n], pb1 = XGO[(size_t)1 * 512 + gp * 256 + 128 + n];
    __syncthreads();

#define ACCS(m) { float4 hm = h4[m];                                        \
        A0 = fmaf(wa##m##_0, hm.x, A0); A1 = fmaf(wa##m##_1, hm.y, A1);     \
        A2 = fmaf(wa##m##_2, hm.z, A2); A3 = fmaf(wa##m##_3, hm.w, A3);     \
        B0 = fmaf(wb##m##_0, hm.x, B0); B1 = fmaf(wb##m##_1, hm.y, B1);     \
        B2 = fmaf(wb##m##_2, hm.z, B2); B3 = fmaf(wb##m##_3, hm.w, B3); }

#define OSTEP(T, BUF, s) {                                                      \
        const float4* h4 = (const float4*)(&h_s[BUF][0] + (kh ? 208 : 0));      \
        float A0 = 0, A1 = 0, A2 = 0, A3 = 0, B0 = 0, B1 = 0, B2 = 0, B3 = 0;   \
        REP16(ACCS)                                                             \
        float sa = (A0 + A1) + (A2 + A3), sb = (B0 + B1) + (B2 + B3);           \
        sa += __shfl_xor(sa, 1, 64); sb += __shfl_xor(sb, 1, 64);               \
        sa += pa##s; sb += pb##s;                                               \
        float ga = gp ? tanhfast(sa) : sigf(sa);                                \
        float gb = sigf(sb);                                                    \
        float qa = __shfl_xor(ga, 2, 64), qb = __shfl_xor(gb, 2, 64);           \
        float gi = gp ? qa : ga, gf = gp ? qb : gb;                             \
        float gg = gp ? ga : qa, go = gp ? gb : qb;                             \
        c = gf * c + gi * gg;                                                   \
        float hh = go * tanhfast(c);                                            \
        if ((tid & 3) == 0) {                                                   \
            h_s[(BUF) ^ 1][n] = hh;                                             \
            if (n >= 64) h_s[(BUF) ^ 1][144 + n] = hh;                          \
            HS[(size_t)(T) * 128 + n] = hh;                                     \
        }                                                                       \
        sync_lds(); }

    for (int t = 0; t < NN; t += 2) {
        // prefetch 2 steps ahead (tail over-reads <=3 rows into adjacent
        // workspace; values never used)
        float na0 = XGO[(size_t)(t + 2) * 512 + gp * 256 + n];
        float nb0 = XGO[(size_t)(t + 2) * 512 + gp * 256 + 128 + n];
        float na1 = XGO[(size_t)(t + 3) * 512 + gp * 256 + n];
        float nb1 = XGO[(size_t)(t + 3) * 512 + gp * 256 + 128 + n];
        OSTEP(t + 0, 0, 0)
        OSTEP(t + 1, 1, 1)
        pa0 = na0; pb0 = nb0; pa1 = na1; pb1 = nb1;
    }
#undef OSTEP
#undef ACCS
}

// ---------------------------------------------------------------------------
// Sequential o-LSTM, H=64. 256 threads: thread = (n = tid>>2, gate-pair
// gg = (tid>>1)&1, K-half kh = tid&1). 64 NAMED SCALAR weights (2 cols x
// 32 K). Staggered dual-copy h (copy B at +80, R6-proven). One barrier/step.
// ---------------------------------------------------------------------------
__global__ __launch_bounds__(256, 1) void olstm64_kernel(const float* __restrict__ XGO,
                                                         const float* __restrict__ Whh,
                                                         float* __restrict__ HS) {
    __shared__ __align__(16) float h_s[2][144];
    const int tid = threadIdx.x;
    const int kh = tid & 1;
    const int gg = (tid >> 1) & 1;   // 0: gates (i,f)  1: gates (g,o)
    const int n = tid >> 2;          // 0..63

    const float4* wap = (const float4*)(Whh + (size_t)(gg * 128 + n) * 64 + kh * 32);
    const float4* wbp = (const float4*)(Whh + (size_t)(gg * 128 + 64 + n) * 64 + kh * 32);
#define DWS64(m) float4 ta##m = wap[m], tb##m = wbp[m];                                           \
    float wa##m##_0 = ta##m.x, wa##m##_1 = ta##m.y, wa##m##_2 = ta##m.z, wa##m##_3 = ta##m.w;     \
    float wb##m##_0 = tb##m.x, wb##m##_1 = tb##m.y, wb##m##_2 = tb##m.z, wb##m##_3 = tb##m.w;
    REP8L(DWS64)
#undef DWS64
#define PIN64(m) asm volatile("" : "+v"(wa##m##_0), "+v"(wa##m##_1), "+v"(wa##m##_2), "+v"(wa##m##_3), \
                                   "+v"(wb##m##_0), "+v"(wb##m##_1), "+v"(wb##m##_2), "+v"(wb##m##_3));
    REP8L(PIN64)
#undef PIN64

    for (int e = tid; e < 2 * 144; e += 256) ((float*)h_s)[e] = 0.f;
    float c = 0.f;

    float pa0 = XGO[(size_t)0 * 256 + gg * 128 + n], pb0 = XGO[(size_t)0 * 256 + gg * 128 + 64 + n];
    float pa1 = XGO[(size_t)1 * 256 + gg * 128 + n], pb1 = XGO[(size_t)1 * 256 + gg * 128 + 64 + n];
    __syncthreads();

#define ACCS64(m) { float4 hm = h4[m];                                      \
        A0 = fmaf(wa##m##_0, hm.x, A0); A1 = fmaf(wa##m##_1, hm.y, A1);     \
        A2 = fmaf(wa##m##_2, hm.z, A2); A3 = fmaf(wa##m##_3, hm.w, A3);     \
        B0 = fmaf(wb##m##_0, hm.x, B0); B1 = fmaf(wb##m##_1, hm.y, B1);     \
        B2 = fmaf(wb##m##_2, hm.z, B2); B3 = fmaf(wb##m##_3, hm.w, B3); }

#define OSTEP64(T, BUF, s) {                                                    \
        const float4* h4 = (const float4*)(&h_s[BUF][0] + (kh ? 112 : 0));      \
        float A0 = 0, A1 = 0, A2 = 0, A3 = 0, B0 = 0, B1 = 0, B2 = 0, B3 = 0;   \
        REP8L(ACCS64)                                                           \
        float sa = (A0 + A1) + (A2 + A3), sb = (B0 + B1) + (B2 + B3);           \
        sa += __shfl_xor(sa, 1, 64); sb += __shfl_xor(sb, 1, 64);               \
        sa += pa##s; sb += pb##s;                                               \
        float ga = gg ? tanhfast(sa) : sigf(sa);                                \
        float gb = sigf(sb);                                                    \
        float qa = __shfl_xor(ga, 2, 64), qb = __shfl_xor(gb, 2, 64);           \
        float gi = gg ? qa : ga, gf = gg ? qb : gb;                             \
        float gG = gg ? ga : qa, go = gg ? gb : qb;                             \
        c = gf * c + gi * gG;                                                   \
        float hh = go * tanhfast(c);                                            \
        if ((tid & 3) == 0) {                                                   \
            h_s[(BUF) ^ 1][n] = hh;                                             \
            if (n >= 32) h_s[(BUF) ^ 1][80 + n] = hh;                           \
            HS[(size_t)(T) * 64 + n] = hh;                                      \
        }                                                                       \
        sync_lds(); }

    for (int t = 0; t < NN; t += 2) {
        float na0 = XGO[(size_t)(t + 2) * 256 + gg * 128 + n];
        float nb0 = XGO[(size_t)(t + 2) * 256 + gg * 128 + 64 + n];
        float na1 = XGO[(size_t)(t + 3) * 256 + gg * 128 + n];
        float nb1 = XGO[(size_t)(t + 3) * 256 + gg * 128 + 64 + n];
        OSTEP64(t + 0, 0, 0)
        OSTEP64(t + 1, 1, 1)
        pa0 = na0; pb0 = nb0; pa1 = na1; pb1 = nb1;
    }
#undef OSTEP64
#undef ACCS64
}

// ---------------------------------------------------------------------------
// Fused relu + row L2-normalize (rows of 128), one wave per row.
// ---------------------------------------------------------------------------
__global__ __launch_bounds__(64) void relunorm_kernel(const float* __restrict__ in,
                                                      float* __restrict__ out) {
    int row = blockIdx.x;
    int lane = threadIdx.x;
    float2 v = ((const float2*)(in + (size_t)row * 128))[lane];
    v.x = fmaxf(v.x, 0.f);
    v.y = fmaxf(v.y, 0.f);
    float ss = v.x * v.x + v.y * v.y;
#pragma unroll
    for (int off = 32; off; off >>= 1) ss += __shfl_xor(ss, off, 64);
    float inv = 1.0f / fmaxf(sqrtf(ss), 1e-12f);
    float2 o;
    o.x = v.x * inv;
    o.y = v.y * inv;
    ((float2*)(out + (size_t)row * 128))[lane] = o;
}

// ---------------------------------------------------------------------------
extern "C" void kernel_launch(void* const* d_in, const int* in_sizes, int n_in,
                              void* d_out, int out_size, void* d_ws, size_t ws_size,
                              hipStream_t stream) {
    const float* x = (const float*)d_in[0];
    const int* nbr = (const int*)d_in[1];
    const float* Wih_r0 = (const float*)d_in[2];
    const float* Whh_r0 = (const float*)d_in[3];
    const float* bih_r0 = (const float*)d_in[4];
    const float* bhh_r0 = (const float*)d_in[5];
    const float* Wih_o0 = (const float*)d_in[6];
    const float* Whh_o0 = (const float*)d_in[7];
    const float* bih_o0 = (const float*)d_in[8];
    const float* bhh_o0 = (const float*)d_in[9];
    const float* Wlin0  = (const float*)d_in[10];
    const float* blin0  = (const float*)d_in[11];
    const float* bias0  = (const float*)d_in[12];
    const float* Wih_r1 = (const float*)d_in[13];
    const float* Whh_r1 = (const float*)d_in[14];
    const float* bih_r1 = (const float*)d_in[15];
    const float* bhh_r1 = (const float*)d_in[16];
    const float* Wih_o1 = (const float*)d_in[17];
    const float* Whh_o1 = (const float*)d_in[18];
    const float* bih_o1 = (const float*)d_in[19];
    const float* bhh_o1 = (const float*)d_in[20];
    const float* Wlin1  = (const float*)d_in[21];
    const float* blin1  = (const float*)d_in[22];
    const float* bias1  = (const float*)d_in[23];

    // workspace layout (bytes): A 64MB | C 16MB | D 16MB | E 16MB | F 16MB
    char* ws = (char*)d_ws;
    float* A = (float*)(ws);                              // XGX then XGO
    float* C = (float*)(ws + (size_t)64 * 1024 * 1024);   // h_agg
    float* Dt = (float*)(ws + (size_t)80 * 1024 * 1024);  // HS
    float* E = (float*)(ws + (size_t)96 * 1024 * 1024);   // X1
    float* F = (float*)(ws + (size_t)112 * 1024 * 1024);  // lin0 raw

    float* outp = (float*)d_out;

    // ----- layer 0 -----
    gemm_bias<128><<<dim3(NN / 64, 8), 256, 0, stream>>>(x, Wih_r0, bih_r0, bhh_r0, A, 512);
    rlstm_kernel<<<NN / 16, 1024, 0, stream>>>(A, nbr, Whh_r0, C);
    gemm_bias<128><<<dim3(NN / 64, 8), 256, 0, stream>>>(C, Wih_o0, bih_o0, bhh_o0, A, 512);
    olstm128_kernel<<<1, 512, 0, stream>>>(A, Whh_o0, Dt);
    gemm_bias<128><<<dim3(NN / 64, 2), 256, 0, stream>>>(Dt, Wlin0, blin0, bias0, F, 128);
    relunorm_kernel<<<NN, 64, 0, stream>>>(F, E);

    // ----- layer 1 -----
    gemm_bias<128><<<dim3(NN / 64, 8), 256, 0, stream>>>(E, Wih_r1, bih_r1, bhh_r1, A, 512);
    rlstm_kernel<<<NN / 16, 1024, 0, stream>>>(A, nbr, Whh_r1, C);
    gemm_bias<128><<<dim3(NN / 64, 4), 256, 0, stream>>>(C, Wih_o1, bih_o1, bhh_o1, A, 256);
    olstm64_kernel<<<1, 256, 0, stream>>>(A, Whh_o1, Dt);
    gemm_bias<64><<<dim3(NN / 64, 1), 256, 0, stream>>>(Dt, Wlin1, blin1, bias1, outp, 64);
}